// Round 2
// baseline (1077.513 us; speedup 1.0000x reference)
//
#include <hip/hip_runtime.h>
#include <hip/hip_bf16.h>
#include <cstdint>

typedef __bf16 bf16x8 __attribute__((ext_vector_type(8)));
typedef __bf16 bf16x4 __attribute__((ext_vector_type(4)));
typedef float  f4     __attribute__((ext_vector_type(4)));

constexpr int BATCH   = 2;
constexpr int LSEQ    = 2048;
constexpr int NH      = 2048;
constexpr int INNER   = 4096;
constexpr int DSTATE  = 128;
constexpr int CONVD   = 4352;
constexpr int HEADS   = 64;
constexpr int HDIM    = 64;
constexpr int NPROJ   = 8512;
constexpr int NPROJ_P = 8576;
constexpr int NC      = 16;
constexpr int CH      = 128;
constexpr int ROWS    = BATCH * LSEQ;

__device__ __forceinline__ f4 f4zero() { f4 v; v.x=0.f; v.y=0.f; v.z=0.f; v.w=0.f; return v; }

// ---------------- marker fill (diagnostic: distinguishes dead pipeline from zero data) ----
__global__ __launch_bounds__(256) void k_fill(float* __restrict__ p, int n, float val) {
    int i = blockIdx.x * 256 + threadIdx.x;
    if (i < n) p[i] = val;
}

// ---------------- cast f32 -> bf16 ----------------
__global__ __launch_bounds__(256) void k_cast_bf16(const float* __restrict__ in,
                                                   __bf16* __restrict__ out, int n4) {
    int i = blockIdx.x * 256 + threadIdx.x;
    if (i >= n4) return;
    f4 v = ((const f4*)in)[i];
    bf16x4 o;
    o[0] = (__bf16)v.x; o[1] = (__bf16)v.y; o[2] = (__bf16)v.z; o[3] = (__bf16)v.w;
    ((bf16x4*)out)[i] = o;
}

// ---------------- transpose + cast: in f32 (R x C) -> out bf16 (Cp x R) ----------------
__global__ __launch_bounds__(256) void k_transpose_cast(const float* __restrict__ in,
                                                        __bf16* __restrict__ out,
                                                        int R, int C, int Cp) {
    __shared__ float tile[32][33];
    int bn = blockIdx.x * 32, bk = blockIdx.y * 32;
    int tx = threadIdx.x & 31, ty = threadIdx.x >> 5;
#pragma unroll
    for (int i = 0; i < 4; ++i) {
        int k = bk + ty + i * 8, n = bn + tx;
        tile[ty + i * 8][tx] = (k < R && n < C) ? in[(size_t)k * C + n] : 0.f;
    }
    __syncthreads();
#pragma unroll
    for (int i = 0; i < 4; ++i) {
        int n = bn + ty + i * 8, k = bk + tx;
        if (n < Cp && k < R) out[(size_t)n * R + k] = (__bf16)tile[tx][ty + i * 8];
    }
}

// ---------------- GEMM1: zxbcdt = x @ W_in + b_in, epilogue splits z/xBC/dt ----------------
__global__ __launch_bounds__(256) void k_gemm1(const __bf16* __restrict__ A,
                                               const __bf16* __restrict__ Bt,
                                               const float* __restrict__ bias,
                                               __bf16* __restrict__ zf,
                                               __bf16* __restrict__ xbcpre,
                                               float* __restrict__ dtraw) {
    constexpr int K = NH;
    __shared__ __bf16 As[128 * 32];
    __shared__ __bf16 Bs[128 * 32];
    int tid = threadIdx.x;
    int lane = tid & 63, wave = tid >> 6;
    int wr = wave >> 1, wc = wave & 1;
    int mBase = blockIdx.y * 128, nBase = blockIdx.x * 128;
    int srow = tid >> 1, scol = (tid & 1) * 16;
    const __bf16* Ag = A + (size_t)(mBase + srow) * K + scol;
    const __bf16* Bg = Bt + (size_t)(nBase + srow) * K + scol;
    f4 acc[4][4];
#pragma unroll
    for (int i = 0; i < 4; ++i)
#pragma unroll
        for (int j = 0; j < 4; ++j) acc[i][j] = f4zero();
    int kq = (lane >> 4) * 8, rl = lane & 15;
    for (int k0 = 0; k0 < K; k0 += 32) {
        __syncthreads();
        *(uint4*)&As[srow * 32 + scol]     = *(const uint4*)(Ag + k0);
        *(uint4*)&As[srow * 32 + scol + 8] = *(const uint4*)(Ag + k0 + 8);
        *(uint4*)&Bs[srow * 32 + scol]     = *(const uint4*)(Bg + k0);
        *(uint4*)&Bs[srow * 32 + scol + 8] = *(const uint4*)(Bg + k0 + 8);
        __syncthreads();
        bf16x8 af[4], bf[4];
#pragma unroll
        for (int i = 0; i < 4; ++i) {
            af[i] = *(const bf16x8*)&As[(wr * 64 + i * 16 + rl) * 32 + kq];
            bf[i] = *(const bf16x8*)&Bs[(wc * 64 + i * 16 + rl) * 32 + kq];
        }
#pragma unroll
        for (int mi = 0; mi < 4; ++mi)
#pragma unroll
            for (int ni = 0; ni < 4; ++ni)
                acc[mi][ni] = __builtin_amdgcn_mfma_f32_16x16x32_bf16(af[mi], bf[ni], acc[mi][ni], 0, 0, 0);
    }
    int rq = lane >> 4, cl = lane & 15;
#pragma unroll
    for (int ni = 0; ni < 4; ++ni) {
        int col0 = nBase + wc * 64 + ni * 16;
        int col = col0 + cl;
        if (col0 >= NPROJ) continue;  // padded region: discard
        float bv = bias[col];
#pragma unroll
        for (int mi = 0; mi < 4; ++mi) {
#pragma unroll
            for (int j = 0; j < 4; ++j) {
                int row = mBase + wr * 64 + mi * 16 + rq * 4 + j;
                float v = acc[mi][ni][j] + bv;
                if (col0 < INNER) {
                    zf[(size_t)row * INNER + col] = (__bf16)v;
                } else if (col0 < INNER + CONVD) {
                    xbcpre[(size_t)row * CONVD + (col - INNER)] = (__bf16)v;
                } else {
                    dtraw[(size_t)row * HEADS + (col - INNER - CONVD)] = v;
                }
            }
        }
    }
}

// ---------------- GEMM2 (generic): C[M,N](f32) = A[M,K] @ Bt[N,K]^T + bias ----------------
__global__ __launch_bounds__(256) void k_gemm_bf16(const __bf16* __restrict__ A,
                                                   const __bf16* __restrict__ Bt,
                                                   const float* __restrict__ bias,
                                                   float* __restrict__ C, int N, int K) {
    __shared__ __bf16 As[128 * 32];
    __shared__ __bf16 Bs[128 * 32];
    int tid = threadIdx.x;
    int lane = tid & 63, wave = tid >> 6;
    int wr = wave >> 1, wc = wave & 1;
    int mBase = blockIdx.y * 128, nBase = blockIdx.x * 128;
    int srow = tid >> 1, scol = (tid & 1) * 16;
    const __bf16* Ag = A + (size_t)(mBase + srow) * K + scol;
    const __bf16* Bg = Bt + (size_t)(nBase + srow) * K + scol;
    f4 acc[4][4];
#pragma unroll
    for (int i = 0; i < 4; ++i)
#pragma unroll
        for (int j = 0; j < 4; ++j) acc[i][j] = f4zero();
    int kq = (lane >> 4) * 8, rl = lane & 15;
    for (int k0 = 0; k0 < K; k0 += 32) {
        __syncthreads();
        *(uint4*)&As[srow * 32 + scol]     = *(const uint4*)(Ag + k0);
        *(uint4*)&As[srow * 32 + scol + 8] = *(const uint4*)(Ag + k0 + 8);
        *(uint4*)&Bs[srow * 32 + scol]     = *(const uint4*)(Bg + k0);
        *(uint4*)&Bs[srow * 32 + scol + 8] = *(const uint4*)(Bg + k0 + 8);
        __syncthreads();
        bf16x8 af[4], bf[4];
#pragma unroll
        for (int i = 0; i < 4; ++i) {
            af[i] = *(const bf16x8*)&As[(wr * 64 + i * 16 + rl) * 32 + kq];
            bf[i] = *(const bf16x8*)&Bs[(wc * 64 + i * 16 + rl) * 32 + kq];
        }
#pragma unroll
        for (int mi = 0; mi < 4; ++mi)
#pragma unroll
            for (int ni = 0; ni < 4; ++ni)
                acc[mi][ni] = __builtin_amdgcn_mfma_f32_16x16x32_bf16(af[mi], bf[ni], acc[mi][ni], 0, 0, 0);
    }
    int rq = lane >> 4, cl = lane & 15;
#pragma unroll
    for (int ni = 0; ni < 4; ++ni) {
        int col = nBase + wc * 64 + ni * 16 + cl;
        float bv = bias[col];
#pragma unroll
        for (int mi = 0; mi < 4; ++mi)
#pragma unroll
            for (int j = 0; j < 4; ++j) {
                int row = mBase + wr * 64 + mi * 16 + rq * 4 + j;
                C[(size_t)row * N + col] = acc[mi][ni][j] + bv;
            }
    }
}

// ---------------- depthwise causal conv(4) + bias + silu (bf16 in/out) ----------------
__global__ __launch_bounds__(256) void k_conv_silu(const __bf16* __restrict__ xbcpre,
                                                   const float* __restrict__ conv_w,
                                                   const float* __restrict__ conv_b,
                                                   __bf16* __restrict__ xbc) {
    int idx = blockIdx.x * 256 + threadIdx.x;  // ROWS * CONVD/8
    int c8 = idx % (CONVD / 8);
    int bl = idx / (CONVD / 8);
    int l = bl & (LSEQ - 1);
    int c0 = c8 * 8;
    float acc[8];
    const f4* cb4 = (const f4*)(conv_b + c0);
    f4 b0 = cb4[0], b1 = cb4[1];
#pragma unroll
    for (int k = 0; k < 4; ++k) { acc[k] = b0[k]; acc[k + 4] = b1[k]; }
#pragma unroll
    for (int j = 0; j < 4; ++j) {
        int l2 = l + j - 3;
        if (l2 < 0) continue;
        bf16x8 xv = *(const bf16x8*)(xbcpre + (size_t)(bl + j - 3) * CONVD + c0);
        const f4* w4 = (const f4*)(conv_w + j * CONVD + c0);
        f4 w0 = w4[0], w1 = w4[1];
#pragma unroll
        for (int k = 0; k < 4; ++k) {
            acc[k]     += w0[k] * (float)xv[k];
            acc[k + 4] += w1[k] * (float)xv[k + 4];
        }
    }
    bf16x8 o;
#pragma unroll
    for (int k = 0; k < 8; ++k) {
        float a = acc[k];
        o[k] = (__bf16)(a / (1.f + expf(-a)));
    }
    *(bf16x8*)(xbc + (size_t)bl * CONVD + c0) = o;
}

// ---------------- dt = clip(softplus(raw + bias)) ----------------
__global__ __launch_bounds__(256) void k_dt(const float* __restrict__ dtraw,
                                            const float* __restrict__ dt_bias,
                                            float* __restrict__ dtp) {
    int idx = blockIdx.x * 256 + threadIdx.x;  // ROWS*HEADS
    int h = idx & 63;
    float raw = dtraw[idx] + dt_bias[h];
    float sp = raw > 20.f ? raw : log1pf(expf(raw));
    dtp[idx] = fminf(fmaxf(sp, 0.001f), 0.1f);
}

// ---------------- cbT[b,c][s][l] = C[l]·B[s], lower-tri ----------------
__global__ __launch_bounds__(256) void k_cb(const __bf16* __restrict__ xbc,
                                            float* __restrict__ cbT) {
    int bid = blockIdx.x;  // b*128 + c*8 + lg
    int lg = bid & 7, c = (bid >> 3) & 15, b = bid >> 7;
    int tid = threadIdx.x;
    int e0 = lg * 2048 + tid * 8;
    int s = e0 >> 7;
    int l0 = e0 & 127;
    int rowbase = b * LSEQ + c * CH;
    const __bf16* Brow = xbc + (size_t)(rowbase + s) * CONVD + INNER;
    const __bf16* C0 = xbc + (size_t)(rowbase + l0) * CONVD + INNER + DSTATE;
    float acc[8];
#pragma unroll
    for (int j = 0; j < 8; ++j) acc[j] = 0.f;
    for (int n8 = 0; n8 < 16; ++n8) {
        bf16x8 bv = *(const bf16x8*)(Brow + n8 * 8);
        float bfv[8];
#pragma unroll
        for (int k = 0; k < 8; ++k) bfv[k] = (float)bv[k];
#pragma unroll
        for (int j = 0; j < 8; ++j) {
            bf16x8 cv = *(const bf16x8*)(C0 + (size_t)j * CONVD + n8 * 8);
#pragma unroll
            for (int k = 0; k < 8; ++k) acc[j] += bfv[k] * (float)cv[k];
        }
    }
    float* dst = cbT + (((size_t)(b * NC + c)) << 14) + (s << 7) + l0;
#pragma unroll
    for (int j = 0; j < 8; ++j) dst[j] = (s <= l0 + j) ? acc[j] : 0.f;
}

// ---------------- per-(b,c,h): dt-scan + chunk states ----------------
__global__ __launch_bounds__(256) void k_states(const __bf16* __restrict__ xbc,
                                                const float* __restrict__ dtp,
                                                const float* __restrict__ A_log,
                                                __bf16* __restrict__ states,
                                                float* __restrict__ acum_buf,
                                                float* __restrict__ aend_buf) {
    int bid = blockIdx.x;
    int h = bid & 63, c = (bid >> 6) & 15, b = bid >> 10;
    int tid = threadIdx.x;
    __shared__ float s_ac[128], s_dt[128], s_e[128];
    __shared__ float Bsh[64][132];
    __shared__ float Xs[64][68];
    int rowbase = b * LSEQ + c * CH;
    float a_h = -expf(A_log[h]);
    if (tid < 128) {
        float d = dtp[(size_t)(rowbase + tid) * HEADS + h];
        s_dt[tid] = d;
        s_ac[tid] = a_h * d;
    }
    __syncthreads();
    for (int offd = 1; offd < 128; offd <<= 1) {
        float v = 0.f;
        if (tid < 128 && tid >= offd) v = s_ac[tid - offd];
        __syncthreads();
        if (tid < 128) s_ac[tid] += v;
        __syncthreads();
    }
    float aend = s_ac[127];
    if (tid < 128) {
        s_e[tid] = expf(aend - s_ac[tid]) * s_dt[tid];
        acum_buf[(((size_t)(b * HEADS + h)) * NC + c) * CH + tid] = s_ac[tid];
    }
    if (tid == 0) aend_buf[(b * HEADS + h) * NC + c] = aend;

    int pt2 = tid & 15, nt2 = tid >> 4;
    int pp0 = pt2 * 4, n0 = nt2 * 8;
    float acc2[4][8];
#pragma unroll
    for (int i = 0; i < 4; ++i)
#pragma unroll
        for (int j = 0; j < 8; ++j) acc2[i][j] = 0.f;
    for (int ltile = 0; ltile < 2; ++ltile) {
        __syncthreads();
        for (int i = 0; i < 32; ++i) {
            int e = i * 256 + tid;
            int n = e & 127, li = e >> 7;
            Bsh[li][n] = (float)xbc[(size_t)(rowbase + ltile * 64 + li) * CONVD + INNER + n];
        }
        for (int i = 0; i < 16; ++i) {
            int e = i * 256 + tid;
            int p = e & 63, li = e >> 6;
            int l = ltile * 64 + li;
            Xs[li][p] = (float)xbc[(size_t)(rowbase + l) * CONVD + h * HDIM + p] * s_e[l];
        }
        __syncthreads();
        for (int li = 0; li < 64; ++li) {
            f4 x4 = *(const f4*)&Xs[li][pp0];
            f4 ba = *(const f4*)&Bsh[li][n0];
            f4 bb = *(const f4*)&Bsh[li][n0 + 4];
#pragma unroll
            for (int i = 0; i < 4; ++i) {
                float xv = x4[i];
#pragma unroll
                for (int j = 0; j < 4; ++j) {
                    acc2[i][j]     += xv * ba[j];
                    acc2[i][j + 4] += xv * bb[j];
                }
            }
        }
    }
    __bf16* sbase = states + ((size_t)((b * NC + c) * HEADS + h)) * (HDIM * DSTATE);
#pragma unroll
    for (int i = 0; i < 4; ++i) {
        bf16x8 o;
#pragma unroll
        for (int j = 0; j < 8; ++j) o[j] = (__bf16)acc2[i][j];
        *(bf16x8*)(sbase + (size_t)(pp0 + i) * DSTATE + n0) = o;
    }
}

// ---------------- inter-chunk state scan (in place, bf16) ----------------
__global__ __launch_bounds__(256) void k_scan(__bf16* __restrict__ states,
                                              const float* __restrict__ aend_buf) {
    int bh = blockIdx.x;  // b*64+h
    int b = bh >> 6, h = bh & 63;
    int tid = threadIdx.x;
    float run[4][8];
#pragma unroll
    for (int i = 0; i < 4; ++i)
#pragma unroll
        for (int j = 0; j < 8; ++j) run[i][j] = 0.f;
    for (int c = 0; c < NC; ++c) {
        float dec = expf(aend_buf[bh * NC + c]);
        bf16x8* base = (bf16x8*)(states + ((size_t)((b * NC + c) * HEADS + h)) * (HDIM * DSTATE));
#pragma unroll
        for (int i = 0; i < 4; ++i) {
            bf16x8 s = base[i * 256 + tid];
            bf16x8 o;
#pragma unroll
            for (int j = 0; j < 8; ++j) o[j] = (__bf16)run[i][j];
            base[i * 256 + tid] = o;
#pragma unroll
            for (int j = 0; j < 8; ++j) run[i][j] = run[i][j] * dec + (float)s[j];
        }
    }
}

// ---------------- y = y_diag + y_off + D*x, written once (bf16) ----------------
__global__ __launch_bounds__(256) void k_out(const __bf16* __restrict__ xbc,
                                             const float* __restrict__ dtp,
                                             const float* __restrict__ cbT,
                                             const __bf16* __restrict__ prev,
                                             const float* __restrict__ acum_buf,
                                             const float* __restrict__ D_param,
                                             __bf16* __restrict__ ybuf) {
    int bid = blockIdx.x;
    int h = bid & 63, c = (bid >> 6) & 15, b = bid >> 10;
    int tid = threadIdx.x;
    __shared__ float s_ac[128], s_dt[128];
    __shared__ float Ct[64][132];  // also Ms
    __shared__ float Pt[64][68];   // also Xs
    int rowbase = b * LSEQ + c * CH;
    if (tid < 128) {
        s_ac[tid] = acum_buf[(((size_t)(b * HEADS + h)) * NC + c) * CH + tid];
        s_dt[tid] = dtp[(size_t)(rowbase + tid) * HEADS + h];
    }
    int lt = tid & 31, pt = tid >> 5;
    int l0 = lt * 4, p0 = pt * 8;
    float acc[4][8];
#pragma unroll
    for (int i = 0; i < 4; ++i)
#pragma unroll
        for (int j = 0; j < 8; ++j) acc[i][j] = 0.f;

    // phase 1: y_off = C · prev  (sum over n)
    const __bf16* pbase = prev + ((size_t)((b * NC + c) * HEADS + h)) * (HDIM * DSTATE);
    for (int nt = 0; nt < 2; ++nt) {
        __syncthreads();
        for (int i = 0; i < 16; ++i) {
            int e = i * 256 + tid;
            int ni = e & 63, p = e >> 6;
            Pt[ni][p] = (float)pbase[(size_t)p * DSTATE + nt * 64 + ni];
        }
        for (int i = 0; i < 32; ++i) {
            int e = i * 256 + tid;
            int ni = e & 63, l = e >> 6;
            Ct[ni][l] = (float)xbc[(size_t)(rowbase + l) * CONVD + INNER + DSTATE + nt * 64 + ni];
        }
        __syncthreads();
        for (int ni = 0; ni < 64; ++ni) {
            f4 c4 = *(const f4*)&Ct[ni][l0];
            f4 pa = *(const f4*)&Pt[ni][p0];
            f4 pb = *(const f4*)&Pt[ni][p0 + 4];
#pragma unroll
            for (int i = 0; i < 4; ++i) {
                float cv = c4[i];
#pragma unroll
                for (int j = 0; j < 4; ++j) {
                    acc[i][j]     += cv * pa[j];
                    acc[i][j + 4] += cv * pb[j];
                }
            }
        }
    }
#pragma unroll
    for (int i = 0; i < 4; ++i) {
        float el = expf(s_ac[l0 + i]);
#pragma unroll
        for (int j = 0; j < 8; ++j) acc[i][j] *= el;
    }

    // phase 2: y_diag = M · x  (sum over s, masked)
    const size_t cbbase = ((size_t)(b * NC + c)) << 14;
    for (int st = 0; st < 2; ++st) {
        __syncthreads();
        for (int i = 0; i < 32; ++i) {
            int e = i * 256 + tid;
            int si = e >> 7, l = e & 127;
            int s = st * 64 + si;
            float m = 0.f;
            if (s <= l) m = cbT[cbbase + ((size_t)s << 7) + l] * expf(s_ac[l] - s_ac[s]) * s_dt[s];
            Ct[si][l] = m;
        }
        for (int i = 0; i < 16; ++i) {
            int e = i * 256 + tid;
            int p = e & 63, si = e >> 6;
            Pt[si][p] = (float)xbc[(size_t)(rowbase + st * 64 + si) * CONVD + h * HDIM + p];
        }
        __syncthreads();
        for (int si = 0; si < 64; ++si) {
            f4 m4 = *(const f4*)&Ct[si][l0];
            f4 xa = *(const f4*)&Pt[si][p0];
            f4 xb = *(const f4*)&Pt[si][p0 + 4];
#pragma unroll
            for (int i = 0; i < 4; ++i) {
                float mv = m4[i];
#pragma unroll
                for (int j = 0; j < 4; ++j) {
                    acc[i][j]     += mv * xa[j];
                    acc[i][j + 4] += mv * xb[j];
                }
            }
        }
    }

    float dh = D_param[h];
#pragma unroll
    for (int i = 0; i < 4; ++i) {
        bf16x8 xv = *(const bf16x8*)(xbc + (size_t)(rowbase + l0 + i) * CONVD + h * HDIM + p0);
        bf16x8 o;
#pragma unroll
        for (int j = 0; j < 8; ++j) o[j] = (__bf16)(acc[i][j] + dh * (float)xv[j]);
        *(bf16x8*)(ybuf + (size_t)(rowbase + l0 + i) * INNER + h * HDIM + p0) = o;
    }
}

// ---------------- gate (silu(z)) + RMSNorm, in place on ybuf ----------------
__global__ __launch_bounds__(256) void k_gate_norm(__bf16* __restrict__ ybuf,
                                                   const __bf16* __restrict__ zf,
                                                   const float* __restrict__ norm_w) {
    int row = blockIdx.x, tid = threadIdx.x;
    bf16x8* yrow = (bf16x8*)(ybuf + (size_t)row * INNER);
    const bf16x8* zrow = (const bf16x8*)(zf + (size_t)row * INNER);
    float v[2][8];
    float ss = 0.f;
#pragma unroll
    for (int i = 0; i < 2; ++i) {
        bf16x8 yv = yrow[i * 256 + tid];
        bf16x8 zv = zrow[i * 256 + tid];
#pragma unroll
        for (int j = 0; j < 8; ++j) {
            float z = (float)zv[j];
            float t = (float)yv[j] * (z / (1.f + expf(-z)));
            v[i][j] = t;
            ss += t * t;
        }
    }
#pragma unroll
    for (int off = 32; off > 0; off >>= 1) ss += __shfl_down(ss, off, 64);
    __shared__ float red[4];
    __shared__ float scs;
    if ((tid & 63) == 0) red[tid >> 6] = ss;
    __syncthreads();
    if (tid == 0) scs = rsqrtf((red[0] + red[1] + red[2] + red[3]) * (1.f / INNER) + 1e-6f);
    __syncthreads();
    float scale = scs;
#pragma unroll
    for (int i = 0; i < 2; ++i) {
        const f4* nw = (const f4*)(norm_w + (i * 256 + tid) * 8);
        f4 w0 = nw[0], w1 = nw[1];
        bf16x8 o;
#pragma unroll
        for (int j = 0; j < 4; ++j) {
            o[j]     = (__bf16)(v[i][j]     * scale * w0[j]);
            o[j + 4] = (__bf16)(v[i][j + 4] * scale * w1[j]);
        }
        yrow[i * 256 + tid] = o;
    }
}

extern "C" void kernel_launch(void* const* d_in, const int* in_sizes, int n_in,
                              void* d_out, int out_size, void* d_ws, size_t ws_size,
                              hipStream_t stream) {
    const float* x       = (const float*)d_in[0];
    const float* W_in    = (const float*)d_in[1];
    const float* b_in    = (const float*)d_in[2];
    const float* conv_w  = (const float*)d_in[3];
    const float* conv_b  = (const float*)d_in[4];
    const float* A_log   = (const float*)d_in[5];
    const float* dt_bias = (const float*)d_in[6];
    const float* D_par   = (const float*)d_in[7];
    const float* norm_w  = (const float*)d_in[8];
    const float* W_out   = (const float*)d_in[9];
    const float* b_out   = (const float*)d_in[10];
    float* out = (float*)d_out;

    char* ws = (char*)d_ws;
    // ---- arena (total ~158 MB) ----
    constexpr size_t SZ_XBF    = (size_t)ROWS * NH * 2;        // 16,777,216
    constexpr size_t SZ_WTIN   = (size_t)NPROJ_P * NH * 2;     // 35,127,296
    constexpr size_t SZ_R1     = SZ_XBF + SZ_WTIN;             // 51,904,512
    constexpr size_t SZ_ZF     = (size_t)ROWS * INNER * 2;     // 33,554,432
    constexpr size_t SZ_XBC    = (size_t)ROWS * CONVD * 2;     // 35,651,584
    constexpr size_t SZ_DTRAW  = (size_t)ROWS * HEADS * 4;     //  1,048,576
    constexpr size_t SZ_STATES = (size_t)BATCH * NC * HEADS * HDIM * DSTATE * 2;  // 33,554,432
    constexpr size_t SZ_CBT    = (size_t)BATCH * NC * CH * CH * 4;                //  2,097,152
    constexpr size_t SZ_ACUM   = (size_t)BATCH * HEADS * NC * CH * 4;             //  1,048,576
    constexpr size_t SZ_AEND   = (size_t)BATCH * HEADS * NC * 4;                  //      8,192

    // phase-1 (GEMM1) residents:
    __bf16* xbf    = (__bf16*)(ws);
    __bf16* wtin   = (__bf16*)(ws + SZ_XBF);
    __bf16* zf     = (__bf16*)(ws + SZ_R1);
    __bf16* xbcpre = (__bf16*)(ws + SZ_R1 + SZ_ZF);
    __bf16* xbc    = (__bf16*)(ws + SZ_R1 + SZ_ZF + SZ_XBC);
    float*  dtraw  = (float*) (ws + SZ_R1 + SZ_ZF + 2 * SZ_XBC);
    // phase-2 residents aliasing R1 (xbf+wtin dead after GEMM1):
    __bf16* states = (__bf16*)(ws);
    float*  cbT    = (float*) (ws + SZ_STATES);
    float*  acum   = (float*) (ws + SZ_STATES + SZ_CBT);
    float*  aend   = (float*) (ws + SZ_STATES + SZ_CBT + SZ_ACUM);
    float*  dtp    = (float*) (ws + SZ_STATES + SZ_CBT + SZ_ACUM + SZ_AEND);
    // phase-3 aliases:
    __bf16* ybuf   = xbcpre;                 // xbcpre dead after conv
    __bf16* wtout  = xbc;                    // xbc dead after k_out

    (void)ws_size; (void)in_sizes; (void)n_in; (void)out_size;

    // diagnostic marker: if pipeline dies mid-way, absmax ~1000 instead of 5
    k_fill<<<(out_size + 255) / 256, 256, 0, stream>>>(out, out_size, 1000.0f);

    k_cast_bf16<<<(ROWS * NH / 4 + 255) / 256, 256, 0, stream>>>(x, xbf, ROWS * NH / 4);
    k_transpose_cast<<<dim3(NPROJ_P / 32, NH / 32), 256, 0, stream>>>(W_in, wtin, NH, NPROJ, NPROJ_P);

    k_gemm1<<<dim3(NPROJ_P / 128, ROWS / 128), 256, 0, stream>>>(xbf, wtin, b_in, zf, xbcpre, dtraw);

    k_conv_silu<<<ROWS * (CONVD / 8) / 256, 256, 0, stream>>>(xbcpre, conv_w, conv_b, xbc);
    k_dt<<<ROWS * HEADS / 256, 256, 0, stream>>>(dtraw, dt_bias, dtp);
    k_cb<<<BATCH * NC * 8, 256, 0, stream>>>(xbc, cbT);
    k_states<<<BATCH * NC * HEADS, 256, 0, stream>>>(xbc, dtp, A_log, states, acum, aend);
    k_scan<<<BATCH * HEADS, 256, 0, stream>>>(states, aend);
    k_out<<<BATCH * NC * HEADS, 256, 0, stream>>>(xbc, dtp, cbT, states, acum, D_par, ybuf);
    k_gate_norm<<<ROWS, 256, 0, stream>>>(ybuf, zf, norm_w);

    k_transpose_cast<<<dim3(NH / 32, INNER / 32), 256, 0, stream>>>(W_out, wtout, INNER, NH, NH);
    k_gemm_bf16<<<dim3(NH / 128, ROWS / 128), 256, 0, stream>>>(ybuf, wtout, b_out, out, NH, INNER);
}

// Round 3
// 513.600 us; speedup vs baseline: 2.0980x; 2.0980x over previous
//
#include <hip/hip_runtime.h>
#include <hip/hip_bf16.h>
#include <cstdint>

typedef __bf16 bf16x8 __attribute__((ext_vector_type(8)));
typedef __bf16 bf16x4 __attribute__((ext_vector_type(4)));
typedef float  f4     __attribute__((ext_vector_type(4)));

constexpr int BATCH   = 2;
constexpr int LSEQ    = 2048;
constexpr int NH      = 2048;
constexpr int INNER   = 4096;
constexpr int DSTATE  = 128;
constexpr int CONVD   = 4352;
constexpr int HEADS   = 64;
constexpr int HDIM    = 64;
constexpr int NPROJ   = 8512;
constexpr int NPROJ_P = 8576;
constexpr int NC      = 16;
constexpr int CH      = 128;
constexpr int ROWS    = BATCH * LSEQ;
constexpr int NBC     = BATCH * NC;   // 32

__device__ __forceinline__ f4 f4zero() { f4 v; v.x=0.f; v.y=0.f; v.z=0.f; v.w=0.f; return v; }

// async global->LDS, 16B per lane. lds base must be wave-uniform (HW adds lane*16).
__device__ __forceinline__ void gload16(const __bf16* g, __bf16* l) {
    __builtin_amdgcn_global_load_lds((const __attribute__((address_space(1))) void*)g,
                                     (__attribute__((address_space(3))) void*)l, 16, 0, 0);
}

// ---------------- cast f32 -> bf16 ----------------
__global__ __launch_bounds__(256) void k_cast_bf16(const float* __restrict__ in,
                                                   __bf16* __restrict__ out, int n4) {
    int i = blockIdx.x * 256 + threadIdx.x;
    if (i >= n4) return;
    f4 v = ((const f4*)in)[i];
    bf16x4 o;
    o[0] = (__bf16)v.x; o[1] = (__bf16)v.y; o[2] = (__bf16)v.z; o[3] = (__bf16)v.w;
    ((bf16x4*)out)[i] = o;
}

// ---------------- transpose + cast: in f32 (R x C) -> out bf16 (Cp x R) ----------------
__global__ __launch_bounds__(256) void k_transpose_cast(const float* __restrict__ in,
                                                        __bf16* __restrict__ out,
                                                        int R, int C, int Cp) {
    __shared__ float tile[32][33];
    int bn = blockIdx.x * 32, bk = blockIdx.y * 32;
    int tx = threadIdx.x & 31, ty = threadIdx.x >> 5;
#pragma unroll
    for (int i = 0; i < 4; ++i) {
        int k = bk + ty + i * 8, n = bn + tx;
        tile[ty + i * 8][tx] = (k < R && n < C) ? in[(size_t)k * C + n] : 0.f;
    }
    __syncthreads();
#pragma unroll
    for (int i = 0; i < 4; ++i) {
        int n = bn + ty + i * 8, k = bk + tx;
        if (n < Cp && k < R) out[(size_t)n * R + k] = (__bf16)tile[tx][ty + i * 8];
    }
}

// ---------------- GEMM1 (global_load_lds staging): splits z/xBC/dt ----------------
__global__ __launch_bounds__(256) void k_gemm1(const __bf16* __restrict__ A,
                                               const __bf16* __restrict__ Bt,
                                               const float* __restrict__ bias,
                                               __bf16* __restrict__ zf,
                                               __bf16* __restrict__ xbcpre,
                                               float* __restrict__ dtraw) {
    constexpr int K = NH;
    __shared__ __bf16 As[128 * 32];
    __shared__ __bf16 Bs[128 * 32];
    int tid = threadIdx.x;
    int lane = tid & 63, wave = tid >> 6;
    int wr = wave >> 1, wc = wave & 1;
    int mBase = blockIdx.y * 128, nBase = blockIdx.x * 128;
    int srow = lane >> 2, scol = (lane & 3) * 8;
    const __bf16* ga0 = A  + (size_t)(mBase + wave * 16 + srow) * K + scol;
    const __bf16* ga1 = ga0 + (size_t)64 * K;
    const __bf16* gb0 = Bt + (size_t)(nBase + wave * 16 + srow) * K + scol;
    const __bf16* gb1 = gb0 + (size_t)64 * K;
    __bf16* la0 = As + (wave * 16) * 32;
    __bf16* la1 = As + (64 + wave * 16) * 32;
    __bf16* lb0 = Bs + (wave * 16) * 32;
    __bf16* lb1 = Bs + (64 + wave * 16) * 32;
    f4 acc[4][4];
#pragma unroll
    for (int i = 0; i < 4; ++i)
#pragma unroll
        for (int j = 0; j < 4; ++j) acc[i][j] = f4zero();
    int kq = (lane >> 4) * 8, rl = lane & 15;
    for (int k0 = 0; k0 < K; k0 += 32) {
        __syncthreads();
        gload16(ga0 + k0, la0);
        gload16(ga1 + k0, la1);
        gload16(gb0 + k0, lb0);
        gload16(gb1 + k0, lb1);
        __syncthreads();
        bf16x8 af[4], bf[4];
#pragma unroll
        for (int i = 0; i < 4; ++i) {
            af[i] = *(const bf16x8*)&As[(wr * 64 + i * 16 + rl) * 32 + kq];
            bf[i] = *(const bf16x8*)&Bs[(wc * 64 + i * 16 + rl) * 32 + kq];
        }
#pragma unroll
        for (int mi = 0; mi < 4; ++mi)
#pragma unroll
            for (int ni = 0; ni < 4; ++ni)
                acc[mi][ni] = __builtin_amdgcn_mfma_f32_16x16x32_bf16(af[mi], bf[ni], acc[mi][ni], 0, 0, 0);
    }
    int rq = lane >> 4, cl = lane & 15;
#pragma unroll
    for (int ni = 0; ni < 4; ++ni) {
        int col0 = nBase + wc * 64 + ni * 16;
        int col = col0 + cl;
        if (col0 >= NPROJ) continue;
        float bv = bias[col];
#pragma unroll
        for (int mi = 0; mi < 4; ++mi) {
#pragma unroll
            for (int j = 0; j < 4; ++j) {
                int row = mBase + wr * 64 + mi * 16 + rq * 4 + j;
                float v = acc[mi][ni][j] + bv;
                if (col0 < INNER) {
                    zf[(size_t)row * INNER + col] = (__bf16)v;
                } else if (col0 < INNER + CONVD) {
                    xbcpre[(size_t)row * CONVD + (col - INNER)] = (__bf16)v;
                } else {
                    dtraw[(size_t)row * HEADS + (col - INNER - CONVD)] = v;
                }
            }
        }
    }
}

// ---------------- GEMM2 (global_load_lds staging) ----------------
__global__ __launch_bounds__(256) void k_gemm_bf16(const __bf16* __restrict__ A,
                                                   const __bf16* __restrict__ Bt,
                                                   const float* __restrict__ bias,
                                                   float* __restrict__ C, int N, int K) {
    __shared__ __bf16 As[128 * 32];
    __shared__ __bf16 Bs[128 * 32];
    int tid = threadIdx.x;
    int lane = tid & 63, wave = tid >> 6;
    int wr = wave >> 1, wc = wave & 1;
    int mBase = blockIdx.y * 128, nBase = blockIdx.x * 128;
    int srow = lane >> 2, scol = (lane & 3) * 8;
    const __bf16* ga0 = A  + (size_t)(mBase + wave * 16 + srow) * K + scol;
    const __bf16* ga1 = ga0 + (size_t)64 * K;
    const __bf16* gb0 = Bt + (size_t)(nBase + wave * 16 + srow) * K + scol;
    const __bf16* gb1 = gb0 + (size_t)64 * K;
    __bf16* la0 = As + (wave * 16) * 32;
    __bf16* la1 = As + (64 + wave * 16) * 32;
    __bf16* lb0 = Bs + (wave * 16) * 32;
    __bf16* lb1 = Bs + (64 + wave * 16) * 32;
    f4 acc[4][4];
#pragma unroll
    for (int i = 0; i < 4; ++i)
#pragma unroll
        for (int j = 0; j < 4; ++j) acc[i][j] = f4zero();
    int kq = (lane >> 4) * 8, rl = lane & 15;
    for (int k0 = 0; k0 < K; k0 += 32) {
        __syncthreads();
        gload16(ga0 + k0, la0);
        gload16(ga1 + k0, la1);
        gload16(gb0 + k0, lb0);
        gload16(gb1 + k0, lb1);
        __syncthreads();
        bf16x8 af[4], bf[4];
#pragma unroll
        for (int i = 0; i < 4; ++i) {
            af[i] = *(const bf16x8*)&As[(wr * 64 + i * 16 + rl) * 32 + kq];
            bf[i] = *(const bf16x8*)&Bs[(wc * 64 + i * 16 + rl) * 32 + kq];
        }
#pragma unroll
        for (int mi = 0; mi < 4; ++mi)
#pragma unroll
            for (int ni = 0; ni < 4; ++ni)
                acc[mi][ni] = __builtin_amdgcn_mfma_f32_16x16x32_bf16(af[mi], bf[ni], acc[mi][ni], 0, 0, 0);
    }
    int rq = lane >> 4, cl = lane & 15;
#pragma unroll
    for (int ni = 0; ni < 4; ++ni) {
        int col = nBase + wc * 64 + ni * 16 + cl;
        float bv = bias[col];
#pragma unroll
        for (int mi = 0; mi < 4; ++mi)
#pragma unroll
            for (int j = 0; j < 4; ++j) {
                int row = mBase + wr * 64 + mi * 16 + rq * 4 + j;
                C[(size_t)row * N + col] = acc[mi][ni][j] + bv;
            }
    }
}

// ---------------- depthwise causal conv(4) + bias + silu ----------------
__global__ __launch_bounds__(256) void k_conv_silu(const __bf16* __restrict__ xbcpre,
                                                   const float* __restrict__ conv_w,
                                                   const float* __restrict__ conv_b,
                                                   __bf16* __restrict__ xbc) {
    int idx = blockIdx.x * 256 + threadIdx.x;
    int c8 = idx % (CONVD / 8);
    int bl = idx / (CONVD / 8);
    int l = bl & (LSEQ - 1);
    int c0 = c8 * 8;
    float acc[8];
    const f4* cb4 = (const f4*)(conv_b + c0);
    f4 b0 = cb4[0], b1 = cb4[1];
#pragma unroll
    for (int k = 0; k < 4; ++k) { acc[k] = b0[k]; acc[k + 4] = b1[k]; }
#pragma unroll
    for (int j = 0; j < 4; ++j) {
        int l2 = l + j - 3;
        if (l2 < 0) continue;
        bf16x8 xv = *(const bf16x8*)(xbcpre + (size_t)(bl + j - 3) * CONVD + c0);
        const f4* w4 = (const f4*)(conv_w + j * CONVD + c0);
        f4 w0 = w4[0], w1 = w4[1];
#pragma unroll
        for (int k = 0; k < 4; ++k) {
            acc[k]     += w0[k] * (float)xv[k];
            acc[k + 4] += w1[k] * (float)xv[k + 4];
        }
    }
    bf16x8 o;
#pragma unroll
    for (int k = 0; k < 8; ++k) {
        float a = acc[k];
        o[k] = (__bf16)(a / (1.f + expf(-a)));
    }
    *(bf16x8*)(xbc + (size_t)bl * CONVD + c0) = o;
}

// ---------------- dt = clip(softplus(raw+bias)), stored transposed [b,h][l] ----------------
__global__ __launch_bounds__(256) void k_dt(const float* __restrict__ dtraw,
                                            const float* __restrict__ dt_bias,
                                            float* __restrict__ dtp_t) {
    int idx = blockIdx.x * 256 + threadIdx.x;  // ROWS*HEADS
    int h = idx & 63;
    int bl = idx >> 6;
    int b = bl >> 11, l = bl & (LSEQ - 1);
    float raw = dtraw[idx] + dt_bias[h];
    float sp = raw > 20.f ? raw : log1pf(expf(raw));
    dtp_t[((size_t)(b * HEADS + h)) * LSEQ + l] = fminf(fmaxf(sp, 0.001f), 0.1f);
}

// ---------------- per-(b,c): transpose x-block and B-block ----------------
// xT[bc][pg(4096)][l(128)], BtG[bc][n(128)][l(128)]
__global__ __launch_bounds__(256) void k_transpose_bc(const __bf16* __restrict__ xbc,
                                                      __bf16* __restrict__ xT,
                                                      __bf16* __restrict__ BtG) {
    int bid = blockIdx.x;                 // bc*132 + rt*66 + ct
    int ct = bid % 66;
    int rt = (bid / 66) & 1;
    int bc = bid / 132;
    __shared__ float T[64][65];
    int t = threadIdx.x;
    int lr0 = t >> 3, cg = t & 7;
#pragma unroll
    for (int it = 0; it < 2; ++it) {
        int lr = lr0 + it * 32;
        bf16x8 v = *(const bf16x8*)(xbc + (size_t)(bc * CH + rt * 64 + lr) * CONVD + ct * 64 + cg * 8);
#pragma unroll
        for (int j = 0; j < 8; ++j) T[lr][cg * 8 + j] = (float)v[j];
    }
    __syncthreads();
#pragma unroll
    for (int it = 0; it < 2; ++it) {
        int cl = lr0 + it * 32;
        int c = ct * 64 + cl;
        bf16x8 o;
#pragma unroll
        for (int j = 0; j < 8; ++j) o[j] = (__bf16)T[cg * 8 + j][cl];
        __bf16* dst = (c < INNER)
            ? xT  + ((size_t)bc * INNER + c) * CH + rt * 64 + cg * 8
            : BtG + ((size_t)bc * DSTATE + (c - INNER)) * CH + rt * 64 + cg * 8;
        *(bf16x8*)dst = o;
    }
}

// ---------------- cb[bc][l][s] = C[l]·B[s] (lower-tri) ----------------
__global__ __launch_bounds__(256) void k_cb(const __bf16* __restrict__ xbc,
                                            float* __restrict__ cbT) {
    int bid = blockIdx.x;  // bc*8 + lg
    int lg = bid & 7, bc = bid >> 3;
    int tid = threadIdx.x;
    int e0 = lg * 2048 + tid * 8;
    int l = e0 >> 7;
    int s0 = e0 & 127;
    const __bf16* Crow = xbc + (size_t)(bc * CH + l) * CONVD + INNER + DSTATE;
    const __bf16* B0   = xbc + (size_t)(bc * CH + s0) * CONVD + INNER;
    float acc[8];
#pragma unroll
    for (int j = 0; j < 8; ++j) acc[j] = 0.f;
    for (int n8 = 0; n8 < 16; ++n8) {
        bf16x8 cv = *(const bf16x8*)(Crow + n8 * 8);
        float cf[8];
#pragma unroll
        for (int k = 0; k < 8; ++k) cf[k] = (float)cv[k];
#pragma unroll
        for (int j = 0; j < 8; ++j) {
            bf16x8 bv = *(const bf16x8*)(B0 + (size_t)j * CONVD + n8 * 8);
#pragma unroll
            for (int k = 0; k < 8; ++k) acc[j] += cf[k] * (float)bv[k];
        }
    }
    float* dst = cbT + ((size_t)bc << 14) + (l << 7) + s0;
#pragma unroll
    for (int j = 0; j < 8; ++j) dst[j] = (s0 + j <= l) ? acc[j] : 0.f;
}

// ---------------- k_states (MFMA): states[p][n] = sum_l e[l]*X[l,p]*B[l,n] ----------------
__global__ __launch_bounds__(256) void k_states(const __bf16* __restrict__ xT,
                                                const __bf16* __restrict__ BtG,
                                                const float* __restrict__ dtp_t,
                                                const float* __restrict__ A_log,
                                                __bf16* __restrict__ states,
                                                float* __restrict__ acum_buf,
                                                float* __restrict__ aend_buf) {
    int bid = blockIdx.x;
    int h = bid & 63, c = (bid >> 6) & 15, b = bid >> 10;
    int bc = b * NC + c, bh = b * HEADS + h;
    int tid = threadIdx.x;
    int lane = tid & 63, w = tid >> 6;
    __shared__ __bf16 Ab[64 * 136];    // X^T * e  [p][l]
    __shared__ __bf16 Bb[128 * 136];   // B^T      [n][l]
    __shared__ float s_ac[128], s_dt[128], s_e[128];
    float a_h = -expf(A_log[h]);

    if (tid < 128) {
        float d = dtp_t[(size_t)bh * LSEQ + c * CH + tid];
        s_dt[tid] = d;
        s_ac[tid] = a_h * d;
    }
    __syncthreads();
    for (int offd = 1; offd < 128; offd <<= 1) {
        float v = 0.f;
        if (tid < 128 && tid >= offd) v = s_ac[tid - offd];
        __syncthreads();
        if (tid < 128) s_ac[tid] += v;
        __syncthreads();
    }
    float aend = s_ac[127];
    if (tid < 128) {
        s_e[tid] = expf(aend - s_ac[tid]) * s_dt[tid];
        acum_buf[((size_t)bh * NC + c) * CH + tid] = s_ac[tid];
    }
    if (tid == 0) aend_buf[bh * NC + c] = aend;
    __syncthreads();

    // stage XtE [64][136]
    const __bf16* xrow = xT + ((size_t)bc * INNER + h * HDIM) * CH;
#pragma unroll
    for (int it = 0; it < 4; ++it) {
        int task = it * 256 + tid;
        int p = task >> 4, lg2 = task & 15;
        bf16x8 v = *(const bf16x8*)(xrow + (size_t)p * CH + lg2 * 8);
        bf16x8 o;
#pragma unroll
        for (int j = 0; j < 8; ++j) o[j] = (__bf16)((float)v[j] * s_e[lg2 * 8 + j]);
        *(bf16x8*)&Ab[p * 136 + lg2 * 8] = o;
    }
    // stage Bt [128][136]
    const __bf16* brow = BtG + (size_t)bc * DSTATE * CH;
#pragma unroll
    for (int it = 0; it < 8; ++it) {
        int task = it * 256 + tid;
        int n = task >> 4, lg2 = task & 15;
        *(bf16x8*)&Bb[n * 136 + lg2 * 8] = *(const bf16x8*)(brow + (size_t)n * CH + lg2 * 8);
    }
    __syncthreads();

    int rl = lane & 15, kq = (lane >> 4) * 8, rq = lane >> 4;
    f4 acc[8];
#pragma unroll
    for (int i = 0; i < 8; ++i) acc[i] = f4zero();
#pragma unroll
    for (int ks = 0; ks < 4; ++ks) {
        int k0 = ks * 32;
        bf16x8 a = *(const bf16x8*)&Ab[(w * 16 + rl) * 136 + k0 + kq];
#pragma unroll
        for (int nf = 0; nf < 8; ++nf) {
            bf16x8 bfr = *(const bf16x8*)&Bb[(nf * 16 + rl) * 136 + k0 + kq];
            acc[nf] = __builtin_amdgcn_mfma_f32_16x16x32_bf16(a, bfr, acc[nf], 0, 0, 0);
        }
    }
    __syncthreads();
    // stage result (bf16) into Ab as [p][n] pitch 136
#pragma unroll
    for (int nf = 0; nf < 8; ++nf)
#pragma unroll
        for (int j = 0; j < 4; ++j)
            Ab[(w * 16 + rq * 4 + j) * 136 + nf * 16 + rl] = (__bf16)acc[nf][j];
    __syncthreads();
    __bf16* sbase = states + ((size_t)(bc * HEADS + h)) * (HDIM * DSTATE);
#pragma unroll
    for (int it = 0; it < 4; ++it) {
        int task = it * 256 + tid;
        int p = task >> 4, ng = task & 15;
        *(bf16x8*)(sbase + (size_t)p * DSTATE + ng * 8) = *(const bf16x8*)&Ab[p * 136 + ng * 8];
    }
}

// ---------------- inter-chunk state scan (in place, bf16) ----------------
__global__ __launch_bounds__(256) void k_scan(__bf16* __restrict__ states,
                                              const float* __restrict__ aend_buf) {
    int bh = blockIdx.x;
    int b = bh >> 6, h = bh & 63;
    int tid = threadIdx.x;
    float run[4][8];
#pragma unroll
    for (int i = 0; i < 4; ++i)
#pragma unroll
        for (int j = 0; j < 8; ++j) run[i][j] = 0.f;
    for (int c = 0; c < NC; ++c) {
        float dec = expf(aend_buf[bh * NC + c]);
        bf16x8* base = (bf16x8*)(states + ((size_t)((b * NC + c) * HEADS + h)) * (HDIM * DSTATE));
#pragma unroll
        for (int i = 0; i < 4; ++i) {
            bf16x8 s = base[i * 256 + tid];
            bf16x8 o;
#pragma unroll
            for (int j = 0; j < 8; ++j) o[j] = (__bf16)run[i][j];
            base[i * 256 + tid] = o;
#pragma unroll
            for (int j = 0; j < 8; ++j) run[i][j] = run[i][j] * dec + (float)s[j];
        }
    }
}

// ---------------- k_out (MFMA): y = exp(ac)*C·prev^T + M·X + D*x ----------------
__global__ __launch_bounds__(256) void k_out(const __bf16* __restrict__ xbc,
                                             const __bf16* __restrict__ xT,
                                             const float* __restrict__ dtp_t,
                                             const float* __restrict__ cbT,
                                             const __bf16* __restrict__ prev,
                                             const float* __restrict__ acum_buf,
                                             const float* __restrict__ D_param,
                                             __bf16* __restrict__ ybuf) {
    int bid = blockIdx.x;
    int h = bid & 63, c = (bid >> 6) & 15, b = bid >> 10;
    int bc = b * NC + c, bh = b * HEADS + h;
    int tid = threadIdx.x;
    int lane = tid & 63, w = tid >> 6;
    __shared__ __bf16 Ab[128 * 136];   // C then M; reused as float yT[128][68]
    __shared__ __bf16 Bb[64 * 136];    // prev then X^T
    __shared__ float s_ac[128], s_dt[128];
    if (tid < 128) {
        s_ac[tid] = acum_buf[((size_t)bh * NC + c) * CH + tid];
        s_dt[tid] = dtp_t[(size_t)bh * LSEQ + c * CH + tid];
    }

    // stage C [l][n] (direct layout) and prev [p][n] (direct layout)
#pragma unroll
    for (int it = 0; it < 8; ++it) {
        int task = it * 256 + tid;
        int l = task >> 4, ng = task & 15;
        *(bf16x8*)&Ab[l * 136 + ng * 8] =
            *(const bf16x8*)(xbc + (size_t)(bc * CH + l) * CONVD + INNER + DSTATE + ng * 8);
    }
    const __bf16* pbase = prev + ((size_t)(bc * HEADS + h)) * (HDIM * DSTATE);
#pragma unroll
    for (int it = 0; it < 4; ++it) {
        int task = it * 256 + tid;
        int p = task >> 4, ng = task & 15;
        *(bf16x8*)&Bb[p * 136 + ng * 8] = *(const bf16x8*)(pbase + (size_t)p * DSTATE + ng * 8);
    }
    __syncthreads();

    int rl = lane & 15, kq = (lane >> 4) * 8, rq = lane >> 4;
    f4 acc[2][4];
#pragma unroll
    for (int i = 0; i < 2; ++i)
#pragma unroll
        for (int j = 0; j < 4; ++j) acc[i][j] = f4zero();

    // phase 1: y_off = C · prev^T  (K = n = 128)
#pragma unroll
    for (int ks = 0; ks < 4; ++ks) {
        int k0 = ks * 32;
        bf16x8 a0 = *(const bf16x8*)&Ab[(w * 32 + rl) * 136 + k0 + kq];
        bf16x8 a1 = *(const bf16x8*)&Ab[(w * 32 + 16 + rl) * 136 + k0 + kq];
#pragma unroll
        for (int nf = 0; nf < 4; ++nf) {
            bf16x8 bfr = *(const bf16x8*)&Bb[(nf * 16 + rl) * 136 + k0 + kq];
            acc[0][nf] = __builtin_amdgcn_mfma_f32_16x16x32_bf16(a0, bfr, acc[0][nf], 0, 0, 0);
            acc[1][nf] = __builtin_amdgcn_mfma_f32_16x16x32_bf16(a1, bfr, acc[1][nf], 0, 0, 0);
        }
    }
    // scale by exp(acum[l])
#pragma unroll
    for (int mf = 0; mf < 2; ++mf)
#pragma unroll
        for (int j = 0; j < 4; ++j) {
            float el = expf(s_ac[w * 32 + mf * 16 + rq * 4 + j]);
#pragma unroll
            for (int nf = 0; nf < 4; ++nf) acc[mf][nf][j] *= el;
        }
    __syncthreads();

    // stage M [l][s] and X^T [p][s]
    const float* cbb = cbT + ((size_t)bc << 14);
#pragma unroll
    for (int it = 0; it < 8; ++it) {
        int task = it * 256 + tid;
        int l = task >> 4, sg = task & 15;
        int s0 = sg * 8;
        const f4* cv4 = (const f4*)(cbb + (l << 7) + s0);
        f4 c0 = cv4[0], c1 = cv4[1];
        float acl = s_ac[l];
        bf16x8 o;
#pragma unroll
        for (int j = 0; j < 8; ++j) {
            int s = s0 + j;
            float cj = (j < 4) ? c0[j] : c1[j - 4];
            float m = 0.f;
            if (s <= l) m = cj * expf(acl - s_ac[s]) * s_dt[s];
            o[j] = (__bf16)m;
        }
        *(bf16x8*)&Ab[l * 136 + s0] = o;
    }
    const __bf16* xrow = xT + ((size_t)bc * INNER + h * HDIM) * CH;
#pragma unroll
    for (int it = 0; it < 4; ++it) {
        int task = it * 256 + tid;
        int p = task >> 4, lg2 = task & 15;
        *(bf16x8*)&Bb[p * 136 + lg2 * 8] = *(const bf16x8*)(xrow + (size_t)p * CH + lg2 * 8);
    }
    __syncthreads();

    // phase 2: y += M · X^T  (K = s = 128)
#pragma unroll
    for (int ks = 0; ks < 4; ++ks) {
        int k0 = ks * 32;
        bf16x8 a0 = *(const bf16x8*)&Ab[(w * 32 + rl) * 136 + k0 + kq];
        bf16x8 a1 = *(const bf16x8*)&Ab[(w * 32 + 16 + rl) * 136 + k0 + kq];
#pragma unroll
        for (int nf = 0; nf < 4; ++nf) {
            bf16x8 bfr = *(const bf16x8*)&Bb[(nf * 16 + rl) * 136 + k0 + kq];
            acc[0][nf] = __builtin_amdgcn_mfma_f32_16x16x32_bf16(a0, bfr, acc[0][nf], 0, 0, 0);
            acc[1][nf] = __builtin_amdgcn_mfma_f32_16x16x32_bf16(a1, bfr, acc[1][nf], 0, 0, 0);
        }
    }
    __syncthreads();

    // write acc -> yT (f32, pitch 68) in Ab region
    float* yT = (float*)Ab;
#pragma unroll
    for (int mf = 0; mf < 2; ++mf)
#pragma unroll
        for (int nf = 0; nf < 4; ++nf)
#pragma unroll
            for (int j = 0; j < 4; ++j)
                yT[(w * 32 + mf * 16 + rq * 4 + j) * 68 + nf * 16 + rl] = acc[mf][nf][j];
    __syncthreads();

    // final: y + D*x -> ybuf (coalesced)
    float dh = D_param[h];
#pragma unroll
    for (int it = 0; it < 4; ++it) {
        int task = it * 256 + tid;
        int l = task >> 3, pg = task & 7;
        const f4* yv4 = (const f4*)&yT[l * 68 + pg * 8];
        f4 y0 = yv4[0], y1 = yv4[1];
        bf16x8 xv = *(const bf16x8*)(xbc + (size_t)(bc * CH + l) * CONVD + h * HDIM + pg * 8);
        bf16x8 o;
#pragma unroll
        for (int j = 0; j < 4; ++j) {
            o[j]     = (__bf16)(y0[j] + dh * (float)xv[j]);
            o[j + 4] = (__bf16)(y1[j] + dh * (float)xv[j + 4]);
        }
        *(bf16x8*)(ybuf + (size_t)(bc * CH + l) * INNER + h * HDIM + pg * 8) = o;
    }
}

// ---------------- gate (silu(z)) + RMSNorm, in place on ybuf ----------------
__global__ __launch_bounds__(256) void k_gate_norm(__bf16* __restrict__ ybuf,
                                                   const __bf16* __restrict__ zf,
                                                   const float* __restrict__ norm_w) {
    int row = blockIdx.x, tid = threadIdx.x;
    bf16x8* yrow = (bf16x8*)(ybuf + (size_t)row * INNER);
    const bf16x8* zrow = (const bf16x8*)(zf + (size_t)row * INNER);
    float v[2][8];
    float ss = 0.f;
#pragma unroll
    for (int i = 0; i < 2; ++i) {
        bf16x8 yv = yrow[i * 256 + tid];
        bf16x8 zv = zrow[i * 256 + tid];
#pragma unroll
        for (int j = 0; j < 8; ++j) {
            float z = (float)zv[j];
            float t = (float)yv[j] * (z / (1.f + expf(-z)));
            v[i][j] = t;
            ss += t * t;
        }
    }
#pragma unroll
    for (int off = 32; off > 0; off >>= 1) ss += __shfl_down(ss, off, 64);
    __shared__ float red[4];
    __shared__ float scs;
    if ((tid & 63) == 0) red[tid >> 6] = ss;
    __syncthreads();
    if (tid == 0) scs = rsqrtf((red[0] + red[1] + red[2] + red[3]) * (1.f / INNER) + 1e-6f);
    __syncthreads();
    float scale = scs;
#pragma unroll
    for (int i = 0; i < 2; ++i) {
        const f4* nw = (const f4*)(norm_w + (i * 256 + tid) * 8);
        f4 w0 = nw[0], w1 = nw[1];
        bf16x8 o;
#pragma unroll
        for (int j = 0; j < 4; ++j) {
            o[j]     = (__bf16)(v[i][j]     * scale * w0[j]);
            o[j + 4] = (__bf16)(v[i][j + 4] * scale * w1[j]);
        }
        yrow[i * 256 + tid] = o;
    }
}

extern "C" void kernel_launch(void* const* d_in, const int* in_sizes, int n_in,
                              void* d_out, int out_size, void* d_ws, size_t ws_size,
                              hipStream_t stream) {
    const float* x       = (const float*)d_in[0];
    const float* W_in    = (const float*)d_in[1];
    const float* b_in    = (const float*)d_in[2];
    const float* conv_w  = (const float*)d_in[3];
    const float* conv_b  = (const float*)d_in[4];
    const float* A_log   = (const float*)d_in[5];
    const float* dt_bias = (const float*)d_in[6];
    const float* D_par   = (const float*)d_in[7];
    const float* norm_w  = (const float*)d_in[8];
    const float* W_out   = (const float*)d_in[9];
    const float* b_out   = (const float*)d_in[10];
    float* out = (float*)d_out;

    char* ws = (char*)d_ws;
    constexpr size_t SZ_XBF    = (size_t)ROWS * NH * 2;
    constexpr size_t SZ_WTIN   = (size_t)NPROJ_P * NH * 2;
    constexpr size_t SZ_R1     = SZ_XBF + SZ_WTIN;
    constexpr size_t SZ_ZF     = (size_t)ROWS * INNER * 2;
    constexpr size_t SZ_XBC    = (size_t)ROWS * CONVD * 2;
    constexpr size_t SZ_STATES = (size_t)NBC * HEADS * HDIM * DSTATE * 2;   // 33.55 MB
    constexpr size_t SZ_CBT    = (size_t)NBC * CH * CH * 4;                 //  2.10 MB
    constexpr size_t SZ_ACUM   = (size_t)BATCH * HEADS * NC * CH * 4;       //  1.05 MB
    constexpr size_t SZ_AEND   = (size_t)BATCH * HEADS * NC * 4;
    constexpr size_t SZ_DTP    = (size_t)ROWS * HEADS * 4;

    // phase-1 residents
    __bf16* xbf    = (__bf16*)(ws);
    __bf16* wtin   = (__bf16*)(ws + SZ_XBF);
    __bf16* zf     = (__bf16*)(ws + SZ_R1);
    __bf16* xbcpre = (__bf16*)(ws + SZ_R1 + SZ_ZF);
    __bf16* xbc    = (__bf16*)(ws + SZ_R1 + SZ_ZF + SZ_XBC);
    float*  dtraw  = (float*) (ws + SZ_R1 + SZ_ZF + 2 * SZ_XBC);
    // phase-2 residents aliasing R1 (xbf+wtin dead after GEMM1)
    __bf16* states = (__bf16*)(ws);
    float*  cbT    = (float*) (ws + SZ_STATES);
    float*  acum   = (float*) (ws + SZ_STATES + SZ_CBT);
    float*  aend   = (float*) (ws + SZ_STATES + SZ_CBT + SZ_ACUM);
    float*  dtp_t  = (float*) (ws + SZ_STATES + SZ_CBT + SZ_ACUM + SZ_AEND);
    __bf16* BtG    = (__bf16*)(ws + SZ_STATES + SZ_CBT + SZ_ACUM + SZ_AEND + SZ_DTP);
    // phase-3 aliases
    __bf16* ybuf   = xbcpre;           // dead after conv
    __bf16* wtout  = xbc;              // dead after k_out
    __bf16* xT     = (__bf16*)out;     // d_out as scratch until GEMM2 rewrites it

    (void)ws_size; (void)in_sizes; (void)n_in; (void)out_size;

    k_cast_bf16<<<(ROWS * NH / 4 + 255) / 256, 256, 0, stream>>>(x, xbf, ROWS * NH / 4);
    k_transpose_cast<<<dim3(NPROJ_P / 32, NH / 32), 256, 0, stream>>>(W_in, wtin, NH, NPROJ, NPROJ_P);

    k_gemm1<<<dim3(NPROJ_P / 128, ROWS / 128), 256, 0, stream>>>(xbf, wtin, b_in, zf, xbcpre, dtraw);

    k_conv_silu<<<ROWS * (CONVD / 8) / 256, 256, 0, stream>>>(xbcpre, conv_w, conv_b, xbc);
    k_dt<<<ROWS * HEADS / 256, 256, 0, stream>>>(dtraw, dt_bias, dtp_t);
    k_transpose_bc<<<NBC * 132, 256, 0, stream>>>(xbc, xT, BtG);
    k_cb<<<NBC * 8, 256, 0, stream>>>(xbc, cbT);
    k_states<<<NBC * HEADS, 256, 0, stream>>>(xT, BtG, dtp_t, A_log, states, acum, aend);
    k_scan<<<BATCH * HEADS, 256, 0, stream>>>(states, aend);
    k_out<<<NBC * HEADS, 256, 0, stream>>>(xbc, xT, dtp_t, cbT, states, acum, D_par, ybuf);
    k_gate_norm<<<ROWS, 256, 0, stream>>>(ybuf, zf, norm_w);

    k_transpose_cast<<<dim3(NH / 32, INNER / 32), 256, 0, stream>>>(W_out, wtout, INNER, NH, NH);
    k_gemm_bf16<<<dim3(NH / 128, ROWS / 128), 256, 0, stream>>>(ybuf, wtout, b_out, out, NH, INNER);
}